// Round 4
// baseline (6079.318 us; speedup 1.0000x reference)
//
#include <hip/hip_runtime.h>
#include <cstddef>

#define HD 512
#define FF 2048
#define VOUT 1024
#define KJOINT 2048

typedef short bf16x8 __attribute__((ext_vector_type(8)));
typedef float f32x4 __attribute__((ext_vector_type(4)));

__device__ inline unsigned short f2bf(float f) {
  union { float f; unsigned u; } c{f};
  unsigned r = c.u + 0x7FFFu + ((c.u >> 16) & 1u);
  return (unsigned short)(r >> 16);
}
__device__ inline float bf2f(unsigned short h) {
  union { unsigned u; float f; } c{(unsigned)h << 16};
  return c.f;
}
__device__ inline float fast_tanh(float x) {
  float e = __expf(2.f * x);
  return 1.f - 2.f / (e + 1.f);
}

// ---------------------------------------------------------------------------
// Embedding kernels
// ---------------------------------------------------------------------------
__global__ __launch_bounds__(256) void embed_audio_kernel(
    const float* __restrict__ inp,   // [B,80,T]
    const float* __restrict__ w,     // [512,80]
    const float* __restrict__ bias,  // [512]
    const float* __restrict__ pos,   // [P,512]
    float* __restrict__ x, int T) {
  int bt = blockIdx.x;
  int b = bt / T, t = bt - b * T;
  int tid = threadIdx.x;
  __shared__ __align__(16) float col[80];
  if (tid < 80) col[tid] = inp[((size_t)b * 80 + tid) * T + t];
  __syncthreads();
  for (int h = tid; h < HD; h += 256) {
    const float* wr = w + (size_t)h * 80;
    float acc = 0.f;
#pragma unroll
    for (int c = 0; c < 80; c++) acc += col[c] * wr[c];
    x[(size_t)bt * HD + h] = acc + bias[h] + pos[(size_t)t * HD + h];
  }
}

__global__ __launch_bounds__(256) void embed_label_kernel(
    const int* __restrict__ labels,  // [B,U]
    const float* __restrict__ word,  // [V,512]
    const float* __restrict__ pos,   // [P,512]
    float* __restrict__ y, int U) {
  int bu = blockIdx.x;
  int u = bu % U;
  int tid = threadIdx.x;
  int id = labels[bu];
  for (int h = tid; h < HD; h += 256)
    y[(size_t)bu * HD + h] = word[(size_t)id * HD + h] + pos[(size_t)u * HD + h];
}

// ---------------------------------------------------------------------------
// f32 -> bf16 conversion, 4 elements/thread, n % 1024 == 0
// ---------------------------------------------------------------------------
__global__ __launch_bounds__(256) void cvt_bf16_kernel(
    const float* __restrict__ in, unsigned short* __restrict__ out) {
  size_t i = ((size_t)blockIdx.x * 256 + threadIdx.x) * 4;
  float4 v = *(const float4*)(in + i);
  ushort4 o;
  o.x = f2bf(v.x); o.y = f2bf(v.y); o.z = f2bf(v.z); o.w = f2bf(v.w);
  *(ushort4*)(out + i) = o;
}

// ---------------------------------------------------------------------------
// bf16 MFMA GEMM, 64x64 tile, 256 thr = 4 waves (2x2 of 32x32).
// Two-part row space: rows < Msplit use B0/bias0, rows >= Msplit use B1/bias1.
// A,B f32 in global, converted to bf16 during staging. Reg-prefetch pipeline.
// M%64==0, N%64==0, K%32==0.
// ---------------------------------------------------------------------------
template <int ACT, int OUT_BF16>
__global__ __launch_bounds__(256) void gemm64_kernel(
    const float* __restrict__ A, int lda,
    const float* __restrict__ B0, const float* __restrict__ B1, int ldb,
    const float* __restrict__ bias0, const float* __restrict__ bias1,
    void* __restrict__ Cout, int ldc, int N, int K, int Msplit) {
  __shared__ short As[64 * 40];
  __shared__ short Bs[64 * 40];
  int tid = threadIdx.x;
  int by = blockIdx.y * 64, bx = blockIdx.x * 64;
  const float* Bw = (by < Msplit) ? B0 : B1;
  const float* bias = (by < Msplit) ? bias0 : bias1;
  int lane = tid & 63, w = tid >> 6;
  int wr = w >> 1, wc = w & 1;
  int srow = tid >> 2, sk = (tid & 3) * 8;
  const float* Ap = A + (size_t)(by + srow) * lda + sk;
  const float* Bp = Bw + (size_t)(bx + srow) * ldb + sk;
  short* As_w = As + srow * 40 + sk;
  short* Bs_w = Bs + srow * 40 + sk;
  f32x4 acc[2][2] = {};
  const short* As_r = As + (wr * 32 + (lane & 15)) * 40 + ((lane >> 4) * 8);
  const short* Bs_r = Bs + (wc * 32 + (lane & 15)) * 40 + ((lane >> 4) * 8);
  float4 a0 = *(const float4*)(Ap);
  float4 a1 = *(const float4*)(Ap + 4);
  float4 b0 = *(const float4*)(Bp);
  float4 b1 = *(const float4*)(Bp + 4);
  for (int k0 = 0; k0 < K; k0 += 32) {
    __syncthreads();
    *(ushort4*)(As_w) = ushort4{f2bf(a0.x), f2bf(a0.y), f2bf(a0.z), f2bf(a0.w)};
    *(ushort4*)(As_w + 4) = ushort4{f2bf(a1.x), f2bf(a1.y), f2bf(a1.z), f2bf(a1.w)};
    *(ushort4*)(Bs_w) = ushort4{f2bf(b0.x), f2bf(b0.y), f2bf(b0.z), f2bf(b0.w)};
    *(ushort4*)(Bs_w + 4) = ushort4{f2bf(b1.x), f2bf(b1.y), f2bf(b1.z), f2bf(b1.w)};
    __syncthreads();
    if (k0 + 32 < K) {
      a0 = *(const float4*)(Ap + k0 + 32);
      a1 = *(const float4*)(Ap + k0 + 36);
      b0 = *(const float4*)(Bp + k0 + 32);
      b1 = *(const float4*)(Bp + k0 + 36);
    }
    bf16x8 af0 = *(const bf16x8*)(As_r);
    bf16x8 af1 = *(const bf16x8*)(As_r + 16 * 40);
    bf16x8 bg0 = *(const bf16x8*)(Bs_r);
    bf16x8 bg1 = *(const bf16x8*)(Bs_r + 16 * 40);
    acc[0][0] = __builtin_amdgcn_mfma_f32_16x16x32_bf16(af0, bg0, acc[0][0], 0, 0, 0);
    acc[0][1] = __builtin_amdgcn_mfma_f32_16x16x32_bf16(af0, bg1, acc[0][1], 0, 0, 0);
    acc[1][0] = __builtin_amdgcn_mfma_f32_16x16x32_bf16(af1, bg0, acc[1][0], 0, 0, 0);
    acc[1][1] = __builtin_amdgcn_mfma_f32_16x16x32_bf16(af1, bg1, acc[1][1], 0, 0, 0);
  }
  int col0 = bx + wc * 32 + (lane & 15);
  int row0 = by + wr * 32 + ((lane >> 4) * 4);
#pragma unroll
  for (int ni = 0; ni < 2; ni++) {
    int col = col0 + ni * 16;
    float bi = bias ? bias[col] : 0.f;
#pragma unroll
    for (int mi = 0; mi < 2; mi++) {
#pragma unroll
      for (int j = 0; j < 4; j++) {
        int row = row0 + mi * 16 + j;
        float v = acc[mi][ni][j] + bi;
        if (ACT == 1) v = fmaxf(v, 0.f);
        if (OUT_BF16)
          ((unsigned short*)Cout)[(size_t)row * ldc + col] = f2bf(v);
        else
          ((float*)Cout)[(size_t)row * ldc + col] = v;
      }
    }
  }
}

// ---------------------------------------------------------------------------
// Attention, merged two-part: blockIdx.x < 256 -> audio (S=256, rows b*256),
// >= 256 -> label (S=64, rows 1024 + b*64). Mask all-false.
// ---------------------------------------------------------------------------
__global__ __launch_bounds__(256) void attn_kernel(
    const float* __restrict__ qkv, float* __restrict__ ctx) {
  int qp = blockIdx.x, h = blockIdx.y, b = blockIdx.z;
  int S, rowbase, q;
  if (qp < 256) { S = 256; rowbase = b * 256; q = qp; }
  else          { S = 64;  rowbase = 1024 + b * 64; q = qp - 256; }
  int tid = threadIdx.x;
  __shared__ __align__(16) float qs[64];
  __shared__ float red[256];
  __shared__ float p[256];
  __shared__ float cred[4][64];
  const float* base = qkv + (size_t)rowbase * 1536;
  if (tid < 64) qs[tid] = base[(size_t)q * 1536 + h * 64 + tid];
  __syncthreads();
  float score = -1e30f;
  if (tid < S) {
    const float4* k4 = (const float4*)(base + (size_t)tid * 1536 + 512 + h * 64);
    const float4* q4 = (const float4*)qs;
    float acc = 0.f;
#pragma unroll
    for (int d = 0; d < 16; d++) {
      float4 kk = k4[d], qq = q4[d];
      acc += qq.x * kk.x + qq.y * kk.y + qq.z * kk.z + qq.w * kk.w;
    }
    score = acc * 0.125f;
  }
  red[tid] = score;
  __syncthreads();
  for (int s = 128; s > 0; s >>= 1) {
    if (tid < s) red[tid] = fmaxf(red[tid], red[tid + s]);
    __syncthreads();
  }
  float mx = red[0];
  __syncthreads();
  float e = (tid < S) ? __expf(score - mx) : 0.f;
  red[tid] = e;
  __syncthreads();
  for (int s = 128; s > 0; s >>= 1) {
    if (tid < s) red[tid] += red[tid + s];
    __syncthreads();
  }
  float inv = 1.f / red[0];
  p[tid] = e * inv;
  __syncthreads();
  int d = tid & 63, part = tid >> 6;
  float acc = 0.f;
  for (int j = part; j < S; j += 4)
    acc += p[j] * base[(size_t)j * 1536 + 1024 + h * 64 + d];
  cred[part][d] = acc;
  __syncthreads();
  if (tid < 64) {
    float c = cred[0][tid] + cred[1][tid] + cred[2][tid] + cred[3][tid];
    ctx[((size_t)(rowbase + q)) * HD + h * 64 + tid] = c;
  }
}

// ---------------------------------------------------------------------------
// Residual add + LayerNorm, merged two-part (row >= 1024 -> label params).
// ---------------------------------------------------------------------------
__global__ __launch_bounds__(256) void add_ln_kernel(
    float* __restrict__ x, const float* __restrict__ y,
    const float* __restrict__ s0, const float* __restrict__ b0,
    const float* __restrict__ s1, const float* __restrict__ b1) {
  int row = blockIdx.x, tid = threadIdx.x;
  const float* s = (row < 1024) ? s0 : s1;
  const float* bsh = (row < 1024) ? b0 : b1;
  float* xr = x + (size_t)row * HD;
  const float* yr = y + (size_t)row * HD;
  float v0 = xr[tid] + yr[tid];
  float v1 = xr[tid + 256] + yr[tid + 256];
  __shared__ float rs_[256], rq_[256];
  rs_[tid] = v0 + v1;
  rq_[tid] = v0 * v0 + v1 * v1;
  __syncthreads();
  for (int st = 128; st > 0; st >>= 1) {
    if (tid < st) { rs_[tid] += rs_[tid + st]; rq_[tid] += rq_[tid + st]; }
    __syncthreads();
  }
  float mean = rs_[0] * (1.f / HD);
  float var = rq_[0] * (1.f / HD) - mean * mean;
  float rstd = rsqrtf(var + 1e-5f);
  xr[tid] = (v0 - mean) * rstd * s[tid] + bsh[tid];
  xr[tid + 256] = (v1 - mean) * rstd * s[tid + 256] + bsh[tid + 256];
}

// ---------------------------------------------------------------------------
// Fused joint + log_softmax.
// Block = 128 rows (2 (b,t) x 64 u) x all 1024 v. 1024 thr = 16 waves
// (2 row-groups x 8 col-groups), each wave 64x128 = 4x8 frags of 16x16x32.
// A = tanh(ha[t]+hl[u]) computed ONCE per element during staging.
// LDS XOR-swizzled (chunk ^= (row>>1)&3) -> 2-way bank conflicts (free).
// Epilogue: in-block log-softmax over the 1024 cols, direct final write.
// ---------------------------------------------------------------------------
__global__ __launch_bounds__(1024) void joint_fused_kernel(
    const unsigned short* __restrict__ ha,  // [B*T,2048] bf16
    const unsigned short* __restrict__ hl,  // [B*U,2048] bf16
    const unsigned short* __restrict__ W,   // [1024,2048] bf16
    const float* __restrict__ wb,           // [1024]
    float* __restrict__ out) {
  __shared__ char AsB[128 * 64];    // 8 KB
  __shared__ char BsB[1024 * 64];   // 64 KB
  __shared__ float red[128 * 8];
  __shared__ float red2[128];
  int tid = threadIdx.x;
  int m0 = blockIdx.x * 128;
  int b = m0 >> 14;
  int lane = tid & 63, w = tid >> 6;
  int wr = w >> 3, wc = w & 7;

  // A staging: thread -> (row = tid>>3, k = (tid&7)*4)
  int arow = tid >> 3;
  int ak = (tid & 7) * 4;
  int bt = (m0 + arow) >> 6;
  int u_s = (m0 + arow) & 63;
  const unsigned short* ha_p = ha + (size_t)bt * KJOINT + ak;
  const unsigned short* hl_p = hl + (size_t)(b * 64 + u_s) * KJOINT + ak;
  char* As_w = AsB + arow * 64 + ((ak * 2) ^ (((arow >> 1) & 3) << 4));
  // B staging: thread -> W row tid, 32 k (4 x bf16x8)
  const unsigned short* W_p = W + (size_t)tid * KJOINT;
  char* Bs_w = BsB + tid * 64;
  int bswz = (tid >> 1) & 3;
  // frag read pointers (swizzle term constant per thread)
  int rswz = ((lane >> 1) & 3) << 4;
  const char* As_r = AsB + (wr * 64 + (lane & 15)) * 64 + (((lane >> 4) * 16) ^ rswz);
  const char* Bs_r = BsB + (wc * 128 + (lane & 15)) * 64 + (((lane >> 4) * 16) ^ rswz);

  f32x4 acc[4][8] = {};
  ushort4 av = *(const ushort4*)(ha_p);
  ushort4 lv = *(const ushort4*)(hl_p);
  bf16x8 wv0 = *(const bf16x8*)(W_p + 0);
  bf16x8 wv1 = *(const bf16x8*)(W_p + 8);
  bf16x8 wv2 = *(const bf16x8*)(W_p + 16);
  bf16x8 wv3 = *(const bf16x8*)(W_p + 24);

  for (int k0 = 0; k0 < KJOINT; k0 += 32) {
    ushort4 hv;
    hv.x = f2bf(fast_tanh(bf2f(av.x) + bf2f(lv.x)));
    hv.y = f2bf(fast_tanh(bf2f(av.y) + bf2f(lv.y)));
    hv.z = f2bf(fast_tanh(bf2f(av.z) + bf2f(lv.z)));
    hv.w = f2bf(fast_tanh(bf2f(av.w) + bf2f(lv.w)));
    __syncthreads();
    *(ushort4*)As_w = hv;
    *(bf16x8*)(Bs_w + ((0 ^ bswz) << 4)) = wv0;
    *(bf16x8*)(Bs_w + ((1 ^ bswz) << 4)) = wv1;
    *(bf16x8*)(Bs_w + ((2 ^ bswz) << 4)) = wv2;
    *(bf16x8*)(Bs_w + ((3 ^ bswz) << 4)) = wv3;
    __syncthreads();
    if (k0 + 32 < KJOINT) {
      av = *(const ushort4*)(ha_p + k0 + 32);
      lv = *(const ushort4*)(hl_p + k0 + 32);
      wv0 = *(const bf16x8*)(W_p + k0 + 32);
      wv1 = *(const bf16x8*)(W_p + k0 + 40);
      wv2 = *(const bf16x8*)(W_p + k0 + 48);
      wv3 = *(const bf16x8*)(W_p + k0 + 56);
    }
    bf16x8 afr[4], bfr[8];
#pragma unroll
    for (int mi = 0; mi < 4; mi++)
      afr[mi] = *(const bf16x8*)(As_r + mi * 16 * 64);
#pragma unroll
    for (int ni = 0; ni < 8; ni++)
      bfr[ni] = *(const bf16x8*)(Bs_r + ni * 16 * 64);
#pragma unroll
    for (int mi = 0; mi < 4; mi++)
#pragma unroll
      for (int ni = 0; ni < 8; ni++)
        acc[mi][ni] = __builtin_amdgcn_mfma_f32_16x16x32_bf16(
            afr[mi], bfr[ni], acc[mi][ni], 0, 0, 0);
  }

  // ---- epilogue: bias + log_softmax + write ----
  int coll = wc * 128 + (lane & 15);
  float bv[8];
#pragma unroll
  for (int ni = 0; ni < 8; ni++) bv[ni] = wb[coll + ni * 16];
#pragma unroll
  for (int mi = 0; mi < 4; mi++)
#pragma unroll
    for (int ni = 0; ni < 8; ni++)
#pragma unroll
      for (int j = 0; j < 4; j++) acc[mi][ni][j] += bv[ni];

  int rbase = wr * 64 + ((lane >> 4) * 4);  // local row for (mi=0, j=0)
  float rmax[4][4];
#pragma unroll
  for (int mi = 0; mi < 4; mi++) {
#pragma unroll
    for (int j = 0; j < 4; j++) {
      float m = acc[mi][0][j];
#pragma unroll
      for (int ni = 1; ni < 8; ni++) m = fmaxf(m, acc[mi][ni][j]);
      m = fmaxf(m, __shfl_xor(m, 1));
      m = fmaxf(m, __shfl_xor(m, 2));
      m = fmaxf(m, __shfl_xor(m, 4));
      m = fmaxf(m, __shfl_xor(m, 8));
      rmax[mi][j] = m;
    }
  }
  if ((lane & 15) == 0) {
#pragma unroll
    for (int mi = 0; mi < 4; mi++)
#pragma unroll
      for (int j = 0; j < 4; j++)
        red[(rbase + mi * 16 + j) * 8 + wc] = rmax[mi][j];
  }
  __syncthreads();
  {
    int r2 = tid >> 3, c2 = tid & 7;
    float v = red[r2 * 8 + c2];
    v = fmaxf(v, __shfl_xor(v, 1));
    v = fmaxf(v, __shfl_xor(v, 2));
    v = fmaxf(v, __shfl_xor(v, 4));
    if (c2 == 0) red2[r2] = v;
  }
  __syncthreads();
#pragma unroll
  for (int mi = 0; mi < 4; mi++)
#pragma unroll
    for (int j = 0; j < 4; j++) rmax[mi][j] = red2[rbase + mi * 16 + j];

  float rsum[4][4];
#pragma unroll
  for (int mi = 0; mi < 4; mi++) {
#pragma unroll
    for (int j = 0; j < 4; j++) {
      float s = 0.f;
#pragma unroll
      for (int ni = 0; ni < 8; ni++) s += __expf(acc[mi][ni][j] - rmax[mi][j]);
      s += __shfl_xor(s, 1);
      s += __shfl_xor(s, 2);
      s += __shfl_xor(s, 4);
      s += __shfl_xor(s, 8);
      rsum[mi][j] = s;
    }
  }
  if ((lane & 15) == 0) {
#pragma unroll
    for (int mi = 0; mi < 4; mi++)
#pragma unroll
      for (int j = 0; j < 4; j++)
        red[(rbase + mi * 16 + j) * 8 + wc] = rsum[mi][j];
  }
  __syncthreads();
  {
    int r2 = tid >> 3, c2 = tid & 7;
    float v = red[r2 * 8 + c2];
    v += __shfl_xor(v, 1);
    v += __shfl_xor(v, 2);
    v += __shfl_xor(v, 4);
    if (c2 == 0) red2[r2] = v;
  }
  __syncthreads();
#pragma unroll
  for (int mi = 0; mi < 4; mi++) {
#pragma unroll
    for (int j = 0; j < 4; j++) {
      int rl = rbase + mi * 16 + j;
      float base = rmax[mi][j] + __logf(red2[rl]);
      size_t row = (size_t)(m0 + rl);
#pragma unroll
      for (int ni = 0; ni < 8; ni++)
        out[row * VOUT + coll + ni * 16] = acc[mi][ni][j] - base;
    }
  }
}

// ---------------------------------------------------------------------------
// Host side
// ---------------------------------------------------------------------------
extern "C" void kernel_launch(void* const* d_in, const int* in_sizes, int n_in,
                              void* d_out, int out_size, void* d_ws, size_t ws_size,
                              hipStream_t stream) {
  const int B = 4, T = 256, U = 64;
  const float* input_values = (const float*)d_in[0];
  const int* labels = (const int*)d_in[1];
  const float* a_lin_w = (const float*)d_in[4];
  const float* a_lin_b = (const float*)d_in[5];
  const float* a_pos = (const float*)d_in[6];
  const float* l_word = (const float*)d_in[7];
  const float* l_pos = (const float*)d_in[8];
  const float* joint_w = (const float*)d_in[9];
  const float* joint_b = (const float*)d_in[10];
  const float* out_w = (const float*)d_in[11];
  const float* out_b = (const float*)d_in[12];

  const float* a_qkv_w = (const float*)d_in[13];
  const float* a_qkv_b = (const float*)d_in[14];
  const float* a_out_w = (const float*)d_in[15];
  const float* a_out_b = (const float*)d_in[16];
  const float* a_ff1_w = (const float*)d_in[17];
  const float* a_ff1_b = (const float*)d_in[18];
  const float* a_ff2_w = (const float*)d_in[19];
  const float* a_ff2_b = (const float*)d_in[20];
  const float* a_ln1_s = (const float*)d_in[21];
  const float* a_ln1_b = (const float*)d_in[22];
  const float* a_ln2_s = (const float*)d_in[23];
  const float* a_ln2_b = (const float*)d_in[24];
  const float* l_qkv_w = (const float*)d_in[25];
  const float* l_qkv_b = (const float*)d_in[26];
  const float* l_out_w = (const float*)d_in[27];
  const float* l_out_b = (const float*)d_in[28];
  const float* l_ff1_w = (const float*)d_in[29];
  const float* l_ff1_b = (const float*)d_in[30];
  const float* l_ff2_w = (const float*)d_in[31];
  const float* l_ff2_b = (const float*)d_in[32];
  const float* l_ln1_s = (const float*)d_in[33];
  const float* l_ln1_b = (const float*)d_in[34];
  const float* l_ln2_s = (const float*)d_in[35];
  const float* l_ln2_b = (const float*)d_in[36];

  // workspace (floats): x_all 1280x512, qkv 1280x1536, ctx 1280x512,
  // tmp 1280x512, ff1 1280x2048; ha/hl/Wb (bf16) alias qkv+ctx after encoders.
  float* ws = (float*)d_ws;
  float* x_all = ws;                       // 655360
  float* qkv   = x_all + 655360;           // 1966080
  float* ctx   = qkv + 1966080;            // 655360
  float* tmp   = ctx + 655360;             // 655360
  float* ff1   = tmp + 655360;             // 2621440
  unsigned short* ha_bf = (unsigned short*)qkv;              // 1048576 f-equiv
  unsigned short* hl_bf = (unsigned short*)(qkv + 1048576);  // 262144 f-equiv
  unsigned short* Wb    = (unsigned short*)(qkv + 1310720);  // 1048576 f-equiv

  // ---- embeddings ----
  embed_audio_kernel<<<B * T, 256, 0, stream>>>(input_values, a_lin_w, a_lin_b,
                                                a_pos, x_all, T);
  embed_label_kernel<<<B * U, 256, 0, stream>>>(labels, l_word, l_pos,
                                                x_all + 1024 * HD, U);

  // ---- merged encoder layers ----
  for (int l = 0; l < 12; l++) {
    bool both = (l < 4);
    int M = both ? 1280 : 1024;
    int gy = M / 64;
    const float* qw1 = both ? l_qkv_w + (size_t)l * 1536 * HD : a_qkv_w;
    const float* qb1 = both ? l_qkv_b + (size_t)l * 1536 : a_qkv_b;
    const float* ow1 = both ? l_out_w + (size_t)l * HD * HD : a_out_w;
    const float* ob1 = both ? l_out_b + (size_t)l * HD : a_out_b;
    const float* f1w1 = both ? l_ff1_w + (size_t)l * FF * HD : a_ff1_w;
    const float* f1b1 = both ? l_ff1_b + (size_t)l * FF : a_ff1_b;
    const float* f2w1 = both ? l_ff2_w + (size_t)l * HD * FF : a_ff2_w;
    const float* f2b1 = both ? l_ff2_b + (size_t)l * HD : a_ff2_b;
    const float* n1s1 = both ? l_ln1_s + (size_t)l * HD : a_ln1_s;
    const float* n1b1 = both ? l_ln1_b + (size_t)l * HD : a_ln1_b;
    const float* n2s1 = both ? l_ln2_s + (size_t)l * HD : a_ln2_s;
    const float* n2b1 = both ? l_ln2_b + (size_t)l * HD : a_ln2_b;

    gemm64_kernel<0, 0><<<dim3(1536 / 64, gy), 256, 0, stream>>>(
        x_all, HD, a_qkv_w + (size_t)l * 1536 * HD, qw1, HD,
        a_qkv_b + (size_t)l * 1536, qb1, qkv, 1536, 1536, HD, 1024);
    attn_kernel<<<dim3(both ? 320 : 256, 8, B), 256, 0, stream>>>(qkv, ctx);
    gemm64_kernel<0, 0><<<dim3(HD / 64, gy), 256, 0, stream>>>(
        ctx, HD, a_out_w + (size_t)l * HD * HD, ow1, HD,
        a_out_b + (size_t)l * HD, ob1, tmp, HD, HD, HD, 1024);
    add_ln_kernel<<<M, 256, 0, stream>>>(x_all, tmp,
        a_ln1_s + (size_t)l * HD, a_ln1_b + (size_t)l * HD, n1s1, n1b1);
    gemm64_kernel<1, 0><<<dim3(FF / 64, gy), 256, 0, stream>>>(
        x_all, HD, a_ff1_w + (size_t)l * FF * HD, f1w1, HD,
        a_ff1_b + (size_t)l * FF, f1b1, ff1, FF, FF, HD, 1024);
    gemm64_kernel<0, 0><<<dim3(HD / 64, gy), 256, 0, stream>>>(
        ff1, FF, a_ff2_w + (size_t)l * HD * FF, f2w1, FF,
        a_ff2_b + (size_t)l * HD, f2b1, tmp, HD, HD, FF, 1024);
    add_ln_kernel<<<M, 256, 0, stream>>>(x_all, tmp,
        a_ln2_s + (size_t)l * HD, a_ln2_b + (size_t)l * HD, n2s1, n2b1);
  }

  // ---- Wb conversion (before overwriting... Wb region is qkv-alias, safe) ----
  cvt_bf16_kernel<<<(VOUT * KJOINT) / 1024, 256, 0, stream>>>(out_w, Wb);

  // ---- joint projections -> bf16 (write over qkv region start) ----
  gemm64_kernel<0, 1><<<dim3(KJOINT / 64, 1024 / 64), 256, 0, stream>>>(
      x_all, HD, joint_w, joint_w, 1024, nullptr, nullptr,
      ha_bf, KJOINT, KJOINT, HD, 1 << 30);
  gemm64_kernel<0, 1><<<dim3(KJOINT / 64, 256 / 64), 256, 0, stream>>>(
      x_all + 1024 * HD, HD, joint_w + HD, joint_w + HD, 1024, joint_b, joint_b,
      hl_bf, KJOINT, KJOINT, HD, 1 << 30);

  // ---- fused joint + log_softmax ----
  joint_fused_kernel<<<(B * T * U) / 128, 1024, 0, stream>>>(
      ha_bf, hl_bf, Wb, out_b, (float*)d_out);
}

// Round 5
// 3666.858 us; speedup vs baseline: 1.6579x; 1.6579x over previous
//
#include <hip/hip_runtime.h>
#include <cstddef>

#define HD 512
#define FF 2048
#define VOUT 1024
#define KJOINT 2048

typedef short bf16x8 __attribute__((ext_vector_type(8)));
typedef float f32x4 __attribute__((ext_vector_type(4)));

__device__ inline unsigned short f2bf(float f) {
  union { float f; unsigned u; } c{f};
  unsigned r = c.u + 0x7FFFu + ((c.u >> 16) & 1u);
  return (unsigned short)(r >> 16);
}
__device__ inline float bf2f(unsigned short h) {
  union { unsigned u; float f; } c{(unsigned)h << 16};
  return c.f;
}
__device__ inline float fast_tanh(float x) {
  float e = __expf(2.f * x);
  return 1.f - 2.f / (e + 1.f);
}

// ---------------------------------------------------------------------------
// Embedding kernels
// ---------------------------------------------------------------------------
__global__ __launch_bounds__(256) void embed_audio_kernel(
    const float* __restrict__ inp,   // [B,80,T]
    const float* __restrict__ w,     // [512,80]
    const float* __restrict__ bias,  // [512]
    const float* __restrict__ pos,   // [P,512]
    float* __restrict__ x, int T) {
  int bt = blockIdx.x;
  int b = bt / T, t = bt - b * T;
  int tid = threadIdx.x;
  __shared__ __align__(16) float col[80];
  if (tid < 80) col[tid] = inp[((size_t)b * 80 + tid) * T + t];
  __syncthreads();
  for (int h = tid; h < HD; h += 256) {
    const float* wr = w + (size_t)h * 80;
    float acc = 0.f;
#pragma unroll
    for (int c = 0; c < 80; c++) acc += col[c] * wr[c];
    x[(size_t)bt * HD + h] = acc + bias[h] + pos[(size_t)t * HD + h];
  }
}

__global__ __launch_bounds__(256) void embed_label_kernel(
    const int* __restrict__ labels,  // [B,U]
    const float* __restrict__ word,  // [V,512]
    const float* __restrict__ pos,   // [P,512]
    float* __restrict__ y, int U) {
  int bu = blockIdx.x;
  int u = bu % U;
  int tid = threadIdx.x;
  int id = labels[bu];
  for (int h = tid; h < HD; h += 256)
    y[(size_t)bu * HD + h] = word[(size_t)id * HD + h] + pos[(size_t)u * HD + h];
}

// ---------------------------------------------------------------------------
// f32 -> bf16 conversion, 4 elements/thread, n % 1024 == 0
// ---------------------------------------------------------------------------
__global__ __launch_bounds__(256) void cvt_bf16_kernel(
    const float* __restrict__ in, unsigned short* __restrict__ out) {
  size_t i = ((size_t)blockIdx.x * 256 + threadIdx.x) * 4;
  float4 v = *(const float4*)(in + i);
  ushort4 o;
  o.x = f2bf(v.x); o.y = f2bf(v.y); o.z = f2bf(v.z); o.w = f2bf(v.w);
  *(ushort4*)(out + i) = o;
}

// ---------------------------------------------------------------------------
// bf16 MFMA GEMM, 64x64 tile, 256 thr = 4 waves (2x2 of 32x32).
// Two-part row space: rows < Msplit use B0/bias0, rows >= Msplit use B1/bias1.
// A,B f32 in global, converted to bf16 during staging. Reg-prefetch pipeline.
// M%64==0, N%64==0, K%32==0.
// ---------------------------------------------------------------------------
template <int ACT, int OUT_BF16>
__global__ __launch_bounds__(256) void gemm64_kernel(
    const float* __restrict__ A, int lda,
    const float* __restrict__ B0, const float* __restrict__ B1, int ldb,
    const float* __restrict__ bias0, const float* __restrict__ bias1,
    void* __restrict__ Cout, int ldc, int N, int K, int Msplit) {
  __shared__ short As[64 * 40];
  __shared__ short Bs[64 * 40];
  int tid = threadIdx.x;
  int by = blockIdx.y * 64, bx = blockIdx.x * 64;
  const float* Bw = (by < Msplit) ? B0 : B1;
  const float* bias = (by < Msplit) ? bias0 : bias1;
  int lane = tid & 63, w = tid >> 6;
  int wr = w >> 1, wc = w & 1;
  int srow = tid >> 2, sk = (tid & 3) * 8;
  const float* Ap = A + (size_t)(by + srow) * lda + sk;
  const float* Bp = Bw + (size_t)(bx + srow) * ldb + sk;
  short* As_w = As + srow * 40 + sk;
  short* Bs_w = Bs + srow * 40 + sk;
  f32x4 acc[2][2] = {};
  const short* As_r = As + (wr * 32 + (lane & 15)) * 40 + ((lane >> 4) * 8);
  const short* Bs_r = Bs + (wc * 32 + (lane & 15)) * 40 + ((lane >> 4) * 8);
  float4 a0 = *(const float4*)(Ap);
  float4 a1 = *(const float4*)(Ap + 4);
  float4 b0 = *(const float4*)(Bp);
  float4 b1 = *(const float4*)(Bp + 4);
  for (int k0 = 0; k0 < K; k0 += 32) {
    __syncthreads();
    *(ushort4*)(As_w) = ushort4{f2bf(a0.x), f2bf(a0.y), f2bf(a0.z), f2bf(a0.w)};
    *(ushort4*)(As_w + 4) = ushort4{f2bf(a1.x), f2bf(a1.y), f2bf(a1.z), f2bf(a1.w)};
    *(ushort4*)(Bs_w) = ushort4{f2bf(b0.x), f2bf(b0.y), f2bf(b0.z), f2bf(b0.w)};
    *(ushort4*)(Bs_w + 4) = ushort4{f2bf(b1.x), f2bf(b1.y), f2bf(b1.z), f2bf(b1.w)};
    __syncthreads();
    if (k0 + 32 < K) {
      a0 = *(const float4*)(Ap + k0 + 32);
      a1 = *(const float4*)(Ap + k0 + 36);
      b0 = *(const float4*)(Bp + k0 + 32);
      b1 = *(const float4*)(Bp + k0 + 36);
    }
    bf16x8 af0 = *(const bf16x8*)(As_r);
    bf16x8 af1 = *(const bf16x8*)(As_r + 16 * 40);
    bf16x8 bg0 = *(const bf16x8*)(Bs_r);
    bf16x8 bg1 = *(const bf16x8*)(Bs_r + 16 * 40);
    acc[0][0] = __builtin_amdgcn_mfma_f32_16x16x32_bf16(af0, bg0, acc[0][0], 0, 0, 0);
    acc[0][1] = __builtin_amdgcn_mfma_f32_16x16x32_bf16(af0, bg1, acc[0][1], 0, 0, 0);
    acc[1][0] = __builtin_amdgcn_mfma_f32_16x16x32_bf16(af1, bg0, acc[1][0], 0, 0, 0);
    acc[1][1] = __builtin_amdgcn_mfma_f32_16x16x32_bf16(af1, bg1, acc[1][1], 0, 0, 0);
  }
  int col0 = bx + wc * 32 + (lane & 15);
  int row0 = by + wr * 32 + ((lane >> 4) * 4);
#pragma unroll
  for (int ni = 0; ni < 2; ni++) {
    int col = col0 + ni * 16;
    float bi = bias ? bias[col] : 0.f;
#pragma unroll
    for (int mi = 0; mi < 2; mi++) {
#pragma unroll
      for (int j = 0; j < 4; j++) {
        int row = row0 + mi * 16 + j;
        float v = acc[mi][ni][j] + bi;
        if (ACT == 1) v = fmaxf(v, 0.f);
        if (OUT_BF16)
          ((unsigned short*)Cout)[(size_t)row * ldc + col] = f2bf(v);
        else
          ((float*)Cout)[(size_t)row * ldc + col] = v;
      }
    }
  }
}

// ---------------------------------------------------------------------------
// Attention, merged two-part: blockIdx.x < 256 -> audio (S=256, rows b*256),
// >= 256 -> label (S=64, rows 1024 + b*64). Mask all-false.
// ---------------------------------------------------------------------------
__global__ __launch_bounds__(256) void attn_kernel(
    const float* __restrict__ qkv, float* __restrict__ ctx) {
  int qp = blockIdx.x, h = blockIdx.y, b = blockIdx.z;
  int S, rowbase, q;
  if (qp < 256) { S = 256; rowbase = b * 256; q = qp; }
  else          { S = 64;  rowbase = 1024 + b * 64; q = qp - 256; }
  int tid = threadIdx.x;
  __shared__ __align__(16) float qs[64];
  __shared__ float red[256];
  __shared__ float p[256];
  __shared__ float cred[4][64];
  const float* base = qkv + (size_t)rowbase * 1536;
  if (tid < 64) qs[tid] = base[(size_t)q * 1536 + h * 64 + tid];
  __syncthreads();
  float score = -1e30f;
  if (tid < S) {
    const float4* k4 = (const float4*)(base + (size_t)tid * 1536 + 512 + h * 64);
    const float4* q4 = (const float4*)qs;
    float acc = 0.f;
#pragma unroll
    for (int d = 0; d < 16; d++) {
      float4 kk = k4[d], qq = q4[d];
      acc += qq.x * kk.x + qq.y * kk.y + qq.z * kk.z + qq.w * kk.w;
    }
    score = acc * 0.125f;
  }
  red[tid] = score;
  __syncthreads();
  for (int s = 128; s > 0; s >>= 1) {
    if (tid < s) red[tid] = fmaxf(red[tid], red[tid + s]);
    __syncthreads();
  }
  float mx = red[0];
  __syncthreads();
  float e = (tid < S) ? __expf(score - mx) : 0.f;
  red[tid] = e;
  __syncthreads();
  for (int s = 128; s > 0; s >>= 1) {
    if (tid < s) red[tid] += red[tid + s];
    __syncthreads();
  }
  float inv = 1.f / red[0];
  p[tid] = e * inv;
  __syncthreads();
  int d = tid & 63, part = tid >> 6;
  float acc = 0.f;
  for (int j = part; j < S; j += 4)
    acc += p[j] * base[(size_t)j * 1536 + 1024 + h * 64 + d];
  cred[part][d] = acc;
  __syncthreads();
  if (tid < 64) {
    float c = cred[0][tid] + cred[1][tid] + cred[2][tid] + cred[3][tid];
    ctx[((size_t)(rowbase + q)) * HD + h * 64 + tid] = c;
  }
}

// ---------------------------------------------------------------------------
// Residual add + LayerNorm, merged two-part (row >= 1024 -> label params).
// ---------------------------------------------------------------------------
__global__ __launch_bounds__(256) void add_ln_kernel(
    float* __restrict__ x, const float* __restrict__ y,
    const float* __restrict__ s0, const float* __restrict__ b0,
    const float* __restrict__ s1, const float* __restrict__ b1) {
  int row = blockIdx.x, tid = threadIdx.x;
  const float* s = (row < 1024) ? s0 : s1;
  const float* bsh = (row < 1024) ? b0 : b1;
  float* xr = x + (size_t)row * HD;
  const float* yr = y + (size_t)row * HD;
  float v0 = xr[tid] + yr[tid];
  float v1 = xr[tid + 256] + yr[tid + 256];
  __shared__ float rs_[256], rq_[256];
  rs_[tid] = v0 + v1;
  rq_[tid] = v0 * v0 + v1 * v1;
  __syncthreads();
  for (int st = 128; st > 0; st >>= 1) {
    if (tid < st) { rs_[tid] += rs_[tid + st]; rq_[tid] += rq_[tid + st]; }
    __syncthreads();
  }
  float mean = rs_[0] * (1.f / HD);
  float var = rq_[0] * (1.f / HD) - mean * mean;
  float rstd = rsqrtf(var + 1e-5f);
  xr[tid] = (v0 - mean) * rstd * s[tid] + bsh[tid];
  xr[tid + 256] = (v1 - mean) * rstd * s[tid + 256] + bsh[tid + 256];
}

// ---------------------------------------------------------------------------
// Fused joint + log_softmax, v2 (no-spill geometry).
// Block = 64 rows (ONE (b,t), all 64 u) x all 1024 v. 512 thr = 8 waves,
// each wave 64x128 = 4x8 frags of 16x16x32. acc[4][8] = 128 VGPR;
// __launch_bounds__(512,2) -> 256-reg budget, 1 block/CU.
// tanh computed ONCE per (row,k) element (no redundancy).
// LDS XOR-swizzled (16B chunk ^= (row>>1)&3) -> 2-way conflicts (free).
// Epilogue: in-block log-softmax over 1024 cols, direct final write.
// ---------------------------------------------------------------------------
__global__ __launch_bounds__(512, 2) void joint_fused_kernel(
    const unsigned short* __restrict__ ha,  // [B*T,2048] bf16
    const unsigned short* __restrict__ hl,  // [B*U,2048] bf16
    const unsigned short* __restrict__ W,   // [1024,2048] bf16
    const float* __restrict__ wb,           // [1024]
    float* __restrict__ out) {
  __shared__ char AsB[64 * 64];     // 4 KB
  __shared__ char BsB[1024 * 64];   // 64 KB
  __shared__ float red[64 * 8];
  __shared__ float red2[64];
  int tid = threadIdx.x;
  int bt = blockIdx.x;              // = b*T + t
  int m0 = bt * 64;
  int b = bt >> 8;                  // T = 256
  int lane = tid & 63, wc = tid >> 6;  // 8 col-groups of 128

  // A staging: thread -> (row u = tid>>3, k = (tid&7)*4)
  int arow = tid >> 3;
  int ak = (tid & 7) * 4;
  const unsigned short* ha_p = ha + (size_t)bt * KJOINT + ak;
  const unsigned short* hl_p = hl + (size_t)(b * 64 + arow) * KJOINT + ak;
  char* As_w = AsB + arow * 64 + ((ak * 2) ^ (((arow >> 1) & 3) << 4));

  // B staging: thread -> W rows 2*tid, 2*tid+1 (64 B each per K-step)
  int r0 = tid * 2;
  const unsigned short* Wp0 = W + (size_t)r0 * KJOINT;
  const unsigned short* Wp1 = Wp0 + KJOINT;
  char* Bs_w0 = BsB + r0 * 64;
  char* Bs_w1 = Bs_w0 + 64;
  int bswz = tid & 3;               // == (row>>1)&3 for both rows

  int rswz = (((lane & 15) >> 1) & 3) << 4;
  const char* As_r = AsB + (lane & 15) * 64 + (((lane >> 4) * 16) ^ rswz);
  const char* Bs_r = BsB + (wc * 128 + (lane & 15)) * 64 + (((lane >> 4) * 16) ^ rswz);

  f32x4 acc[4][8] = {};
  ushort4 av = *(const ushort4*)(ha_p);
  ushort4 lv = *(const ushort4*)(hl_p);
  bf16x8 w00 = *(const bf16x8*)(Wp0 + 0);
  bf16x8 w01 = *(const bf16x8*)(Wp0 + 8);
  bf16x8 w02 = *(const bf16x8*)(Wp0 + 16);
  bf16x8 w03 = *(const bf16x8*)(Wp0 + 24);
  bf16x8 w10 = *(const bf16x8*)(Wp1 + 0);
  bf16x8 w11 = *(const bf16x8*)(Wp1 + 8);
  bf16x8 w12 = *(const bf16x8*)(Wp1 + 16);
  bf16x8 w13 = *(const bf16x8*)(Wp1 + 24);

  for (int k0 = 0; k0 < KJOINT; k0 += 32) {
    ushort4 hv;
    hv.x = f2bf(fast_tanh(bf2f(av.x) + bf2f(lv.x)));
    hv.y = f2bf(fast_tanh(bf2f(av.y) + bf2f(lv.y)));
    hv.z = f2bf(fast_tanh(bf2f(av.z) + bf2f(lv.z)));
    hv.w = f2bf(fast_tanh(bf2f(av.w) + bf2f(lv.w)));
    __syncthreads();
    *(ushort4*)As_w = hv;
    *(bf16x8*)(Bs_w0 + ((0 ^ bswz) << 4)) = w00;
    *(bf16x8*)(Bs_w0 + ((1 ^ bswz) << 4)) = w01;
    *(bf16x8*)(Bs_w0 + ((2 ^ bswz) << 4)) = w02;
    *(bf16x8*)(Bs_w0 + ((3 ^ bswz) << 4)) = w03;
    *(bf16x8*)(Bs_w1 + ((0 ^ bswz) << 4)) = w10;
    *(bf16x8*)(Bs_w1 + ((1 ^ bswz) << 4)) = w11;
    *(bf16x8*)(Bs_w1 + ((2 ^ bswz) << 4)) = w12;
    *(bf16x8*)(Bs_w1 + ((3 ^ bswz) << 4)) = w13;
    __syncthreads();
    if (k0 + 32 < KJOINT) {
      av = *(const ushort4*)(ha_p + k0 + 32);
      lv = *(const ushort4*)(hl_p + k0 + 32);
      w00 = *(const bf16x8*)(Wp0 + k0 + 32);
      w01 = *(const bf16x8*)(Wp0 + k0 + 40);
      w02 = *(const bf16x8*)(Wp0 + k0 + 48);
      w03 = *(const bf16x8*)(Wp0 + k0 + 56);
      w10 = *(const bf16x8*)(Wp1 + k0 + 32);
      w11 = *(const bf16x8*)(Wp1 + k0 + 40);
      w12 = *(const bf16x8*)(Wp1 + k0 + 48);
      w13 = *(const bf16x8*)(Wp1 + k0 + 56);
    }
    bf16x8 afr[4], bfr[8];
#pragma unroll
    for (int mi = 0; mi < 4; mi++)
      afr[mi] = *(const bf16x8*)(As_r + mi * 16 * 64);
#pragma unroll
    for (int ni = 0; ni < 8; ni++)
      bfr[ni] = *(const bf16x8*)(Bs_r + ni * 16 * 64);
#pragma unroll
    for (int mi = 0; mi < 4; mi++)
#pragma unroll
      for (int ni = 0; ni < 8; ni++)
        acc[mi][ni] = __builtin_amdgcn_mfma_f32_16x16x32_bf16(
            afr[mi], bfr[ni], acc[mi][ni], 0, 0, 0);
  }

  // ---- epilogue: bias + log_softmax + write ----
  int coll = wc * 128 + (lane & 15);
  float bv[8];
#pragma unroll
  for (int ni = 0; ni < 8; ni++) bv[ni] = wb[coll + ni * 16];
#pragma unroll
  for (int mi = 0; mi < 4; mi++)
#pragma unroll
    for (int ni = 0; ni < 8; ni++)
#pragma unroll
      for (int j = 0; j < 4; j++) acc[mi][ni][j] += bv[ni];

  int rbase = (lane >> 4) * 4;  // local row for (mi=0, j=0)
  float rmax[4][4];
#pragma unroll
  for (int mi = 0; mi < 4; mi++) {
#pragma unroll
    for (int j = 0; j < 4; j++) {
      float m = acc[mi][0][j];
#pragma unroll
      for (int ni = 1; ni < 8; ni++) m = fmaxf(m, acc[mi][ni][j]);
      m = fmaxf(m, __shfl_xor(m, 1));
      m = fmaxf(m, __shfl_xor(m, 2));
      m = fmaxf(m, __shfl_xor(m, 4));
      m = fmaxf(m, __shfl_xor(m, 8));
      rmax[mi][j] = m;
    }
  }
  if ((lane & 15) == 0) {
#pragma unroll
    for (int mi = 0; mi < 4; mi++)
#pragma unroll
      for (int j = 0; j < 4; j++)
        red[(rbase + mi * 16 + j) * 8 + wc] = rmax[mi][j];
  }
  __syncthreads();
  {
    int r2 = tid >> 3, c2 = tid & 7;
    float v = red[r2 * 8 + c2];
    v = fmaxf(v, __shfl_xor(v, 1));
    v = fmaxf(v, __shfl_xor(v, 2));
    v = fmaxf(v, __shfl_xor(v, 4));
    if (c2 == 0) red2[r2] = v;
  }
  __syncthreads();
#pragma unroll
  for (int mi = 0; mi < 4; mi++)
#pragma unroll
    for (int j = 0; j < 4; j++) rmax[mi][j] = red2[rbase + mi * 16 + j];

  float rsum[4][4];
#pragma unroll
  for (int mi = 0; mi < 4; mi++) {
#pragma unroll
    for (int j = 0; j < 4; j++) {
      float s = 0.f;
#pragma unroll
      for (int ni = 0; ni < 8; ni++) s += __expf(acc[mi][ni][j] - rmax[mi][j]);
      s += __shfl_xor(s, 1);
      s += __shfl_xor(s, 2);
      s += __shfl_xor(s, 4);
      s += __shfl_xor(s, 8);
      rsum[mi][j] = s;
    }
  }
  if ((lane & 15) == 0) {
#pragma unroll
    for (int mi = 0; mi < 4; mi++)
#pragma unroll
      for (int j = 0; j < 4; j++)
        red[(rbase + mi * 16 + j) * 8 + wc] = rsum[mi][j];
  }
  __syncthreads();
  {
    int r2 = tid >> 3, c2 = tid & 7;
    float v = red[r2 * 8 + c2];
    v += __shfl_xor(v, 1);
    v += __shfl_xor(v, 2);
    v += __shfl_xor(v, 4);
    if (c2 == 0) red2[r2] = v;
  }
  __syncthreads();
#pragma unroll
  for (int mi = 0; mi < 4; mi++) {
#pragma unroll
    for (int j = 0; j < 4; j++) {
      int rl = rbase + mi * 16 + j;
      float base = rmax[mi][j] + __logf(red2[rl]);
      size_t row = (size_t)m0 + rl;
#pragma unroll
      for (int ni = 0; ni < 8; ni++)
        out[row * VOUT + coll + ni * 16] = acc[mi][ni][j] - base;
    }
  }
}

// ---------------------------------------------------------------------------
// Host side
// ---------------------------------------------------------------------------
extern "C" void kernel_launch(void* const* d_in, const int* in_sizes, int n_in,
                              void* d_out, int out_size, void* d_ws, size_t ws_size,
                              hipStream_t stream) {
  const int B = 4, T = 256, U = 64;
  const float* input_values = (const float*)d_in[0];
  const int* labels = (const int*)d_in[1];
  const float* a_lin_w = (const float*)d_in[4];
  const float* a_lin_b = (const float*)d_in[5];
  const float* a_pos = (const float*)d_in[6];
  const float* l_word = (const float*)d_in[7];
  const float* l_pos = (const float*)d_in[8];
  const float* joint_w = (const float*)d_in[9];
  const float* joint_b = (const float*)d_in[10];
  const float* out_w = (const float*)d_in[11];
  const float* out_b = (const float*)d_in[12];

  const float* a_qkv_w = (const float*)d_in[13];
  const float* a_qkv_b = (const float*)d_in[14];
  const float* a_out_w = (const float*)d_in[15];
  const float* a_out_b = (const float*)d_in[16];
  const float* a_ff1_w = (const float*)d_in[17];
  const float* a_ff1_b = (const float*)d_in[18];
  const float* a_ff2_w = (const float*)d_in[19];
  const float* a_ff2_b = (const float*)d_in[20];
  const float* a_ln1_s = (const float*)d_in[21];
  const float* a_ln1_b = (const float*)d_in[22];
  const float* a_ln2_s = (const float*)d_in[23];
  const float* a_ln2_b = (const float*)d_in[24];
  const float* l_qkv_w = (const float*)d_in[25];
  const float* l_qkv_b = (const float*)d_in[26];
  const float* l_out_w = (const float*)d_in[27];
  const float* l_out_b = (const float*)d_in[28];
  const float* l_ff1_w = (const float*)d_in[29];
  const float* l_ff1_b = (const float*)d_in[30];
  const float* l_ff2_w = (const float*)d_in[31];
  const float* l_ff2_b = (const float*)d_in[32];
  const float* l_ln1_s = (const float*)d_in[33];
  const float* l_ln1_b = (const float*)d_in[34];
  const float* l_ln2_s = (const float*)d_in[35];
  const float* l_ln2_b = (const float*)d_in[36];

  // workspace (floats): x_all 1280x512, qkv 1280x1536, ctx 1280x512,
  // tmp 1280x512, ff1 1280x2048; ha/hl/Wb (bf16) alias qkv after encoders.
  float* ws = (float*)d_ws;
  float* x_all = ws;                       // 655360
  float* qkv   = x_all + 655360;           // 1966080
  float* ctx   = qkv + 1966080;            // 655360
  float* tmp   = ctx + 655360;             // 655360
  float* ff1   = tmp + 655360;             // 2621440
  unsigned short* ha_bf = (unsigned short*)qkv;              // 1048576 f-equiv
  unsigned short* hl_bf = (unsigned short*)(qkv + 1048576);  // 262144 f-equiv
  unsigned short* Wb    = (unsigned short*)(qkv + 1310720);  // 1048576 f-equiv

  // ---- embeddings ----
  embed_audio_kernel<<<B * T, 256, 0, stream>>>(input_values, a_lin_w, a_lin_b,
                                                a_pos, x_all, T);
  embed_label_kernel<<<B * U, 256, 0, stream>>>(labels, l_word, l_pos,
                                                x_all + 1024 * HD, U);

  // ---- merged encoder layers ----
  for (int l = 0; l < 12; l++) {
    bool both = (l < 4);
    int M = both ? 1280 : 1024;
    int gy = M / 64;
    const float* qw1 = both ? l_qkv_w + (size_t)l * 1536 * HD : a_qkv_w;
    const float* qb1 = both ? l_qkv_b + (size_t)l * 1536 : a_qkv_b;
    const float* ow1 = both ? l_out_w + (size_t)l * HD * HD : a_out_w;
    const float* ob1 = both ? l_out_b + (size_t)l * HD : a_out_b;
    const float* f1w1 = both ? l_ff1_w + (size_t)l * FF * HD : a_ff1_w;
    const float* f1b1 = both ? l_ff1_b + (size_t)l * FF : a_ff1_b;
    const float* f2w1 = both ? l_ff2_w + (size_t)l * HD * FF : a_ff2_w;
    const float* f2b1 = both ? l_ff2_b + (size_t)l * HD : a_ff2_b;
    const float* n1s1 = both ? l_ln1_s + (size_t)l * HD : a_ln1_s;
    const float* n1b1 = both ? l_ln1_b + (size_t)l * HD : a_ln1_b;
    const float* n2s1 = both ? l_ln2_s + (size_t)l * HD : a_ln2_s;
    const float* n2b1 = both ? l_ln2_b + (size_t)l * HD : a_ln2_b;

    gemm64_kernel<0, 0><<<dim3(1536 / 64, gy), 256, 0, stream>>>(
        x_all, HD, a_qkv_w + (size_t)l * 1536 * HD, qw1, HD,
        a_qkv_b + (size_t)l * 1536, qb1, qkv, 1536, 1536, HD, 1024);
    attn_kernel<<<dim3(both ? 320 : 256, 8, B), 256, 0, stream>>>(qkv, ctx);
    gemm64_kernel<0, 0><<<dim3(HD / 64, gy), 256, 0, stream>>>(
        ctx, HD, a_out_w + (size_t)l * HD * HD, ow1, HD,
        a_out_b + (size_t)l * HD, ob1, tmp, HD, HD, HD, 1024);
    add_ln_kernel<<<M, 256, 0, stream>>>(x_all, tmp,
        a_ln1_s + (size_t)l * HD, a_ln1_b + (size_t)l * HD, n1s1, n1b1);
    gemm64_kernel<1, 0><<<dim3(FF / 64, gy), 256, 0, stream>>>(
        x_all, HD, a_ff1_w + (size_t)l * FF * HD, f1w1, HD,
        a_ff1_b + (size_t)l * FF, f1b1, ff1, FF, FF, HD, 1024);
    gemm64_kernel<0, 0><<<dim3(HD / 64, gy), 256, 0, stream>>>(
        ff1, FF, a_ff2_w + (size_t)l * HD * FF, f2w1, FF,
        a_ff2_b + (size_t)l * HD, f2b1, tmp, HD, HD, FF, 1024);
    add_ln_kernel<<<M, 256, 0, stream>>>(x_all, tmp,
        a_ln2_s + (size_t)l * HD, a_ln2_b + (size_t)l * HD, n2s1, n2b1);
  }

  // ---- Wb conversion ----
  cvt_bf16_kernel<<<(VOUT * KJOINT) / 1024, 256, 0, stream>>>(out_w, Wb);

  // ---- joint projections -> bf16 ----
  gemm64_kernel<0, 1><<<dim3(KJOINT / 64, 1024 / 64), 256, 0, stream>>>(
      x_all, HD, joint_w, joint_w, 1024, nullptr, nullptr,
      ha_bf, KJOINT, KJOINT, HD, 1 << 30);
  gemm64_kernel<0, 1><<<dim3(KJOINT / 64, 256 / 64), 256, 0, stream>>>(
      x_all + 1024 * HD, HD, joint_w + HD, joint_w + HD, 1024, joint_b, joint_b,
      hl_bf, KJOINT, KJOINT, HD, 1 << 30);

  // ---- fused joint + log_softmax ----
  joint_fused_kernel<<<B * T, 512, 0, stream>>>(
      ha_bf, hl_bf, Wb, out_b, (float*)d_out);
}

// Round 6
// 3358.446 us; speedup vs baseline: 1.8102x; 1.0918x over previous
//
#include <hip/hip_runtime.h>
#include <cstddef>

#define HD 512
#define FF 2048
#define VOUT 1024
#define KJOINT 2048

typedef short bf16x8 __attribute__((ext_vector_type(8)));
typedef float f32x4 __attribute__((ext_vector_type(4)));

__device__ inline unsigned short f2bf(float f) {
  union { float f; unsigned u; } c{f};
  unsigned r = c.u + 0x7FFFu + ((c.u >> 16) & 1u);
  return (unsigned short)(r >> 16);
}
__device__ inline float bf2f(unsigned short h) {
  union { unsigned u; float f; } c{(unsigned)h << 16};
  return c.f;
}
__device__ inline float fast_tanh(float x) {
  float e = __expf(2.f * x);
  return 1.f - 2.f / (e + 1.f);
}

// ---------------------------------------------------------------------------
// Embedding kernels
// ---------------------------------------------------------------------------
__global__ __launch_bounds__(256) void embed_audio_kernel(
    const float* __restrict__ inp,   // [B,80,T]
    const float* __restrict__ w,     // [512,80]
    const float* __restrict__ bias,  // [512]
    const float* __restrict__ pos,   // [P,512]
    float* __restrict__ x, int T) {
  int bt = blockIdx.x;
  int b = bt / T, t = bt - b * T;
  int tid = threadIdx.x;
  __shared__ __align__(16) float col[80];
  if (tid < 80) col[tid] = inp[((size_t)b * 80 + tid) * T + t];
  __syncthreads();
  for (int h = tid; h < HD; h += 256) {
    const float* wr = w + (size_t)h * 80;
    float acc = 0.f;
#pragma unroll
    for (int c = 0; c < 80; c++) acc += col[c] * wr[c];
    x[(size_t)bt * HD + h] = acc + bias[h] + pos[(size_t)t * HD + h];
  }
}

__global__ __launch_bounds__(256) void embed_label_kernel(
    const int* __restrict__ labels,  // [B,U]
    const float* __restrict__ word,  // [V,512]
    const float* __restrict__ pos,   // [P,512]
    float* __restrict__ y, int U) {
  int bu = blockIdx.x;
  int u = bu % U;
  int tid = threadIdx.x;
  int id = labels[bu];
  for (int h = tid; h < HD; h += 256)
    y[(size_t)bu * HD + h] = word[(size_t)id * HD + h] + pos[(size_t)u * HD + h];
}

// ---------------------------------------------------------------------------
// f32 -> bf16 conversion, 4 elements/thread, n % 1024 == 0
// ---------------------------------------------------------------------------
__global__ __launch_bounds__(256) void cvt_bf16_kernel(
    const float* __restrict__ in, unsigned short* __restrict__ out) {
  size_t i = ((size_t)blockIdx.x * 256 + threadIdx.x) * 4;
  float4 v = *(const float4*)(in + i);
  ushort4 o;
  o.x = f2bf(v.x); o.y = f2bf(v.y); o.z = f2bf(v.z); o.w = f2bf(v.w);
  *(ushort4*)(out + i) = o;
}

// ---------------------------------------------------------------------------
// bf16 MFMA GEMM v2, 64x64 tile, BK=64, 256 thr = 4 waves (2x2 of 32x32).
// Rows < Msplit use B0/bias0, else B1/bias1. f32 inputs converted to bf16
// during staging. LDS rows padded to 72 shorts (144 B) -> 2-way conflicts.
// M%64==0, N%64==0, K%64==0.
// ---------------------------------------------------------------------------
template <int ACT, int OUT_BF16>
__global__ __launch_bounds__(256) void gemm64_kernel(
    const float* __restrict__ A, int lda,
    const float* __restrict__ B0, const float* __restrict__ B1, int ldb,
    const float* __restrict__ bias0, const float* __restrict__ bias1,
    void* __restrict__ Cout, int ldc, int N, int K, int Msplit) {
  __shared__ short As[64 * 72];
  __shared__ short Bs[64 * 72];
  int tid = threadIdx.x;
  int by = blockIdx.y * 64, bx = blockIdx.x * 64;
  const float* Bw = (by < Msplit) ? B0 : B1;
  const float* bias = (by < Msplit) ? bias0 : bias1;
  int lane = tid & 63, w = tid >> 6;
  int wr = w >> 1, wc = w & 1;
  int srow = tid >> 2, skq = (tid & 3) * 16;
  const float* Ap = A + (size_t)(by + srow) * lda + skq;
  const float* Bp = Bw + (size_t)(bx + srow) * ldb + skq;
  short* As_w = As + srow * 72 + skq;
  short* Bs_w = Bs + srow * 72 + skq;
  f32x4 acc[2][2] = {};
  const short* As_r = As + (wr * 32 + (lane & 15)) * 72 + ((lane >> 4) * 8);
  const short* Bs_r = Bs + (wc * 32 + (lane & 15)) * 72 + ((lane >> 4) * 8);
  float4 pa0 = *(const float4*)(Ap);
  float4 pa1 = *(const float4*)(Ap + 4);
  float4 pa2 = *(const float4*)(Ap + 8);
  float4 pa3 = *(const float4*)(Ap + 12);
  float4 pb0 = *(const float4*)(Bp);
  float4 pb1 = *(const float4*)(Bp + 4);
  float4 pb2 = *(const float4*)(Bp + 8);
  float4 pb3 = *(const float4*)(Bp + 12);
  for (int k0 = 0; k0 < K; k0 += 64) {
    __syncthreads();
    *(ushort4*)(As_w +  0) = ushort4{f2bf(pa0.x), f2bf(pa0.y), f2bf(pa0.z), f2bf(pa0.w)};
    *(ushort4*)(As_w +  4) = ushort4{f2bf(pa1.x), f2bf(pa1.y), f2bf(pa1.z), f2bf(pa1.w)};
    *(ushort4*)(As_w +  8) = ushort4{f2bf(pa2.x), f2bf(pa2.y), f2bf(pa2.z), f2bf(pa2.w)};
    *(ushort4*)(As_w + 12) = ushort4{f2bf(pa3.x), f2bf(pa3.y), f2bf(pa3.z), f2bf(pa3.w)};
    *(ushort4*)(Bs_w +  0) = ushort4{f2bf(pb0.x), f2bf(pb0.y), f2bf(pb0.z), f2bf(pb0.w)};
    *(ushort4*)(Bs_w +  4) = ushort4{f2bf(pb1.x), f2bf(pb1.y), f2bf(pb1.z), f2bf(pb1.w)};
    *(ushort4*)(Bs_w +  8) = ushort4{f2bf(pb2.x), f2bf(pb2.y), f2bf(pb2.z), f2bf(pb2.w)};
    *(ushort4*)(Bs_w + 12) = ushort4{f2bf(pb3.x), f2bf(pb3.y), f2bf(pb3.z), f2bf(pb3.w)};
    __syncthreads();
    if (k0 + 64 < K) {
      pa0 = *(const float4*)(Ap + k0 + 64);
      pa1 = *(const float4*)(Ap + k0 + 68);
      pa2 = *(const float4*)(Ap + k0 + 72);
      pa3 = *(const float4*)(Ap + k0 + 76);
      pb0 = *(const float4*)(Bp + k0 + 64);
      pb1 = *(const float4*)(Bp + k0 + 68);
      pb2 = *(const float4*)(Bp + k0 + 72);
      pb3 = *(const float4*)(Bp + k0 + 76);
    }
#pragma unroll
    for (int s = 0; s < 2; s++) {
      bf16x8 af0 = *(const bf16x8*)(As_r + s * 32);
      bf16x8 af1 = *(const bf16x8*)(As_r + s * 32 + 16 * 72);
      bf16x8 bg0 = *(const bf16x8*)(Bs_r + s * 32);
      bf16x8 bg1 = *(const bf16x8*)(Bs_r + s * 32 + 16 * 72);
      acc[0][0] = __builtin_amdgcn_mfma_f32_16x16x32_bf16(af0, bg0, acc[0][0], 0, 0, 0);
      acc[0][1] = __builtin_amdgcn_mfma_f32_16x16x32_bf16(af0, bg1, acc[0][1], 0, 0, 0);
      acc[1][0] = __builtin_amdgcn_mfma_f32_16x16x32_bf16(af1, bg0, acc[1][0], 0, 0, 0);
      acc[1][1] = __builtin_amdgcn_mfma_f32_16x16x32_bf16(af1, bg1, acc[1][1], 0, 0, 0);
    }
  }
  int col0 = bx + wc * 32 + (lane & 15);
  int row0 = by + wr * 32 + ((lane >> 4) * 4);
#pragma unroll
  for (int ni = 0; ni < 2; ni++) {
    int col = col0 + ni * 16;
    float bi = bias ? bias[col] : 0.f;
#pragma unroll
    for (int mi = 0; mi < 2; mi++) {
#pragma unroll
      for (int j = 0; j < 4; j++) {
        int row = row0 + mi * 16 + j;
        float v = acc[mi][ni][j] + bi;
        if (ACT == 1) v = fmaxf(v, 0.f);
        if (OUT_BF16)
          ((unsigned short*)Cout)[(size_t)row * ldc + col] = f2bf(v);
        else
          ((float*)Cout)[(size_t)row * ldc + col] = v;
      }
    }
  }
}

// ---------------------------------------------------------------------------
// Attention, merged two-part: blockIdx.x < 256 -> audio (S=256, rows b*256),
// >= 256 -> label (S=64, rows 1024 + b*64). Mask all-false.
// ---------------------------------------------------------------------------
__global__ __launch_bounds__(256) void attn_kernel(
    const float* __restrict__ qkv, float* __restrict__ ctx) {
  int qp = blockIdx.x, h = blockIdx.y, b = blockIdx.z;
  int S, rowbase, q;
  if (qp < 256) { S = 256; rowbase = b * 256; q = qp; }
  else          { S = 64;  rowbase = 1024 + b * 64; q = qp - 256; }
  int tid = threadIdx.x;
  __shared__ __align__(16) float qs[64];
  __shared__ float red[256];
  __shared__ float p[256];
  __shared__ float cred[4][64];
  const float* base = qkv + (size_t)rowbase * 1536;
  if (tid < 64) qs[tid] = base[(size_t)q * 1536 + h * 64 + tid];
  __syncthreads();
  float score = -1e30f;
  if (tid < S) {
    const float4* k4 = (const float4*)(base + (size_t)tid * 1536 + 512 + h * 64);
    const float4* q4 = (const float4*)qs;
    float acc = 0.f;
#pragma unroll
    for (int d = 0; d < 16; d++) {
      float4 kk = k4[d], qq = q4[d];
      acc += qq.x * kk.x + qq.y * kk.y + qq.z * kk.z + qq.w * kk.w;
    }
    score = acc * 0.125f;
  }
  red[tid] = score;
  __syncthreads();
  for (int s = 128; s > 0; s >>= 1) {
    if (tid < s) red[tid] = fmaxf(red[tid], red[tid + s]);
    __syncthreads();
  }
  float mx = red[0];
  __syncthreads();
  float e = (tid < S) ? __expf(score - mx) : 0.f;
  red[tid] = e;
  __syncthreads();
  for (int s = 128; s > 0; s >>= 1) {
    if (tid < s) red[tid] += red[tid + s];
    __syncthreads();
  }
  float inv = 1.f / red[0];
  p[tid] = e * inv;
  __syncthreads();
  int d = tid & 63, part = tid >> 6;
  float acc = 0.f;
  for (int j = part; j < S; j += 4)
    acc += p[j] * base[(size_t)j * 1536 + 1024 + h * 64 + d];
  cred[part][d] = acc;
  __syncthreads();
  if (tid < 64) {
    float c = cred[0][tid] + cred[1][tid] + cred[2][tid] + cred[3][tid];
    ctx[((size_t)(rowbase + q)) * HD + h * 64 + tid] = c;
  }
}

// ---------------------------------------------------------------------------
// Residual add + LayerNorm, merged two-part (row >= 1024 -> label params).
// ---------------------------------------------------------------------------
__global__ __launch_bounds__(256) void add_ln_kernel(
    float* __restrict__ x, const float* __restrict__ y,
    const float* __restrict__ s0, const float* __restrict__ b0,
    const float* __restrict__ s1, const float* __restrict__ b1) {
  int row = blockIdx.x, tid = threadIdx.x;
  const float* s = (row < 1024) ? s0 : s1;
  const float* bsh = (row < 1024) ? b0 : b1;
  float* xr = x + (size_t)row * HD;
  const float* yr = y + (size_t)row * HD;
  float v0 = xr[tid] + yr[tid];
  float v1 = xr[tid + 256] + yr[tid + 256];
  __shared__ float rs_[256], rq_[256];
  rs_[tid] = v0 + v1;
  rq_[tid] = v0 * v0 + v1 * v1;
  __syncthreads();
  for (int st = 128; st > 0; st >>= 1) {
    if (tid < st) { rs_[tid] += rs_[tid + st]; rq_[tid] += rq_[tid + st]; }
    __syncthreads();
  }
  float mean = rs_[0] * (1.f / HD);
  float var = rq_[0] * (1.f / HD) - mean * mean;
  float rstd = rsqrtf(var + 1e-5f);
  xr[tid] = (v0 - mean) * rstd * s[tid] + bsh[tid];
  xr[tid + 256] = (v1 - mean) * rstd * s[tid + 256] + bsh[tid + 256];
}

// ---------------------------------------------------------------------------
// Fused joint + log_softmax, v3: B (W rows) read DIRECTLY global->VGPR
// (W is L2/L3-resident; each element used once per block -> LDS round-trip
// was pure overhead). Block = 64 rows x 1024 cols, 512 thr = 8 waves,
// wave = 64x128 (4x8 frags). A staged in 4KB swizzled LDS, tanh once/elem.
// Reg double-buffer bc/bn for B (static indices). launch_bounds(512,2).
// ---------------------------------------------------------------------------
__global__ __launch_bounds__(512, 2) void joint_fused_kernel(
    const unsigned short* __restrict__ ha,  // [B*T,2048] bf16
    const unsigned short* __restrict__ hl,  // [B*U,2048] bf16
    const unsigned short* __restrict__ W,   // [1024,2048] bf16
    const float* __restrict__ wb,           // [1024]
    float* __restrict__ out) {
  __shared__ char AsB[64 * 64];     // 4 KB
  __shared__ float red[64 * 8];
  __shared__ float red2[64];
  int tid = threadIdx.x;
  int bt = blockIdx.x;              // = b*T + t
  int m0 = bt * 64;
  int b = bt >> 8;                  // T = 256
  int lane = tid & 63, wc = tid >> 6;  // 8 col-groups of 128

  // A staging: thread -> (row u = tid>>3, k = (tid&7)*4)
  int arow = tid >> 3;
  int ak = (tid & 7) * 4;
  const unsigned short* ha_p = ha + (size_t)bt * KJOINT + ak;
  const unsigned short* hl_p = hl + (size_t)(b * 64 + arow) * KJOINT + ak;
  char* As_w = AsB + arow * 64 + ((ak * 2) ^ (((arow >> 1) & 3) << 4));

  int rswz = (((lane & 15) >> 1) & 3) << 4;
  const char* As_r = AsB + (lane & 15) * 64 + (((lane >> 4) * 16) ^ rswz);

  // B lane base: col = wc*128 + (lane&15) + ni*16, k-offset (lane>>4)*8
  const unsigned short* Wl =
      W + ((size_t)(wc * 128 + (lane & 15))) * KJOINT + ((lane >> 4) * 8);

  f32x4 acc[4][8] = {};
  ushort4 av = *(const ushort4*)(ha_p);
  ushort4 lv = *(const ushort4*)(hl_p);
  bf16x8 bc0 = *(const bf16x8*)(Wl + 0 * 16 * KJOINT);
  bf16x8 bc1 = *(const bf16x8*)(Wl + 1 * 16 * KJOINT);
  bf16x8 bc2 = *(const bf16x8*)(Wl + 2 * 16 * KJOINT);
  bf16x8 bc3 = *(const bf16x8*)(Wl + 3 * 16 * KJOINT);
  bf16x8 bc4 = *(const bf16x8*)(Wl + 4 * 16 * KJOINT);
  bf16x8 bc5 = *(const bf16x8*)(Wl + 5 * 16 * KJOINT);
  bf16x8 bc6 = *(const bf16x8*)(Wl + 6 * 16 * KJOINT);
  bf16x8 bc7 = *(const bf16x8*)(Wl + 7 * 16 * KJOINT);

  for (int k0 = 0; k0 < KJOINT; k0 += 32) {
    ushort4 hv;
    hv.x = f2bf(fast_tanh(bf2f(av.x) + bf2f(lv.x)));
    hv.y = f2bf(fast_tanh(bf2f(av.y) + bf2f(lv.y)));
    hv.z = f2bf(fast_tanh(bf2f(av.z) + bf2f(lv.z)));
    hv.w = f2bf(fast_tanh(bf2f(av.w) + bf2f(lv.w)));
    __syncthreads();
    *(ushort4*)As_w = hv;
    __syncthreads();
    bf16x8 bn0, bn1, bn2, bn3, bn4, bn5, bn6, bn7;
    if (k0 + 32 < KJOINT) {
      av = *(const ushort4*)(ha_p + k0 + 32);
      lv = *(const ushort4*)(hl_p + k0 + 32);
      bn0 = *(const bf16x8*)(Wl + 0 * 16 * KJOINT + k0 + 32);
      bn1 = *(const bf16x8*)(Wl + 1 * 16 * KJOINT + k0 + 32);
      bn2 = *(const bf16x8*)(Wl + 2 * 16 * KJOINT + k0 + 32);
      bn3 = *(const bf16x8*)(Wl + 3 * 16 * KJOINT + k0 + 32);
      bn4 = *(const bf16x8*)(Wl + 4 * 16 * KJOINT + k0 + 32);
      bn5 = *(const bf16x8*)(Wl + 5 * 16 * KJOINT + k0 + 32);
      bn6 = *(const bf16x8*)(Wl + 6 * 16 * KJOINT + k0 + 32);
      bn7 = *(const bf16x8*)(Wl + 7 * 16 * KJOINT + k0 + 32);
    }
    bf16x8 afr[4];
#pragma unroll
    for (int mi = 0; mi < 4; mi++)
      afr[mi] = *(const bf16x8*)(As_r + mi * 16 * 64);
#pragma unroll
    for (int mi = 0; mi < 4; mi++) {
      acc[mi][0] = __builtin_amdgcn_mfma_f32_16x16x32_bf16(afr[mi], bc0, acc[mi][0], 0, 0, 0);
      acc[mi][1] = __builtin_amdgcn_mfma_f32_16x16x32_bf16(afr[mi], bc1, acc[mi][1], 0, 0, 0);
      acc[mi][2] = __builtin_amdgcn_mfma_f32_16x16x32_bf16(afr[mi], bc2, acc[mi][2], 0, 0, 0);
      acc[mi][3] = __builtin_amdgcn_mfma_f32_16x16x32_bf16(afr[mi], bc3, acc[mi][3], 0, 0, 0);
      acc[mi][4] = __builtin_amdgcn_mfma_f32_16x16x32_bf16(afr[mi], bc4, acc[mi][4], 0, 0, 0);
      acc[mi][5] = __builtin_amdgcn_mfma_f32_16x16x32_bf16(afr[mi], bc5, acc[mi][5], 0, 0, 0);
      acc[mi][6] = __builtin_amdgcn_mfma_f32_16x16x32_bf16(afr[mi], bc6, acc[mi][6], 0, 0, 0);
      acc[mi][7] = __builtin_amdgcn_mfma_f32_16x16x32_bf16(afr[mi], bc7, acc[mi][7], 0, 0, 0);
    }
    bc0 = bn0; bc1 = bn1; bc2 = bn2; bc3 = bn3;
    bc4 = bn4; bc5 = bn5; bc6 = bn6; bc7 = bn7;
  }

  // ---- epilogue: bias + log_softmax + write ----
  int coll = wc * 128 + (lane & 15);
  float bv[8];
#pragma unroll
  for (int ni = 0; ni < 8; ni++) bv[ni] = wb[coll + ni * 16];
#pragma unroll
  for (int mi = 0; mi < 4; mi++)
#pragma unroll
    for (int ni = 0; ni < 8; ni++)
#pragma unroll
      for (int j = 0; j < 4; j++) acc[mi][ni][j] += bv[ni];

  int rbase = (lane >> 4) * 4;  // local row for (mi=0, j=0)
  float rmax[4][4];
#pragma unroll
  for (int mi = 0; mi < 4; mi++) {
#pragma unroll
    for (int j = 0; j < 4; j++) {
      float m = acc[mi][0][j];
#pragma unroll
      for (int ni = 1; ni < 8; ni++) m = fmaxf(m, acc[mi][ni][j]);
      m = fmaxf(m, __shfl_xor(m, 1));
      m = fmaxf(m, __shfl_xor(m, 2));
      m = fmaxf(m, __shfl_xor(m, 4));
      m = fmaxf(m, __shfl_xor(m, 8));
      rmax[mi][j] = m;
    }
  }
  if ((lane & 15) == 0) {
#pragma unroll
    for (int mi = 0; mi < 4; mi++)
#pragma unroll
      for (int j = 0; j < 4; j++)
        red[(rbase + mi * 16 + j) * 8 + wc] = rmax[mi][j];
  }
  __syncthreads();
  {
    int r2 = tid >> 3, c2 = tid & 7;
    float v = red[r2 * 8 + c2];
    v = fmaxf(v, __shfl_xor(v, 1));
    v = fmaxf(v, __shfl_xor(v, 2));
    v = fmaxf(v, __shfl_xor(v, 4));
    if (c2 == 0) red2[r2] = v;
  }
  __syncthreads();
#pragma unroll
  for (int mi = 0; mi < 4; mi++)
#pragma unroll
    for (int j = 0; j < 4; j++) rmax[mi][j] = red2[rbase + mi * 16 + j];

  float rsum[4][4];
#pragma unroll
  for (int mi = 0; mi < 4; mi++) {
#pragma unroll
    for (int j = 0; j < 4; j++) {
      float s = 0.f;
#pragma unroll
      for (int ni = 0; ni < 8; ni++) s += __expf(acc[mi][ni][j] - rmax[mi][j]);
      s += __shfl_xor(s, 1);
      s += __shfl_xor(s, 2);
      s += __shfl_xor(s, 4);
      s += __shfl_xor(s, 8);
      rsum[mi][j] = s;
    }
  }
  if ((lane & 15) == 0) {
#pragma unroll
    for (int mi = 0; mi < 4; mi++)
#pragma unroll
      for (int j = 0; j < 4; j++)
        red[(rbase + mi * 16 + j) * 8 + wc] = rsum[mi][j];
  }
  __syncthreads();
  {
    int r2 = tid >> 3, c2 = tid & 7;
    float v = red[r2 * 8 + c2];
    v += __shfl_xor(v, 1);
    v += __shfl_xor(v, 2);
    v += __shfl_xor(v, 4);
    if (c2 == 0) red2[r2] = v;
  }
  __syncthreads();
#pragma unroll
  for (int mi = 0; mi < 4; mi++) {
#pragma unroll
    for (int j = 0; j < 4; j++) {
      int rl = rbase + mi * 16 + j;
      float base = rmax[mi][j] + __logf(red2[rl]);
      size_t row = (size_t)m0 + rl;
#pragma unroll
      for (int ni = 0; ni < 8; ni++)
        out[row * VOUT + coll + ni * 16] = acc[mi][ni][j] - base;
    }
  }
}

// ---------------------------------------------------------------------------
// Host side
// ---------------------------------------------------------------------------
extern "C" void kernel_launch(void* const* d_in, const int* in_sizes, int n_in,
                              void* d_out, int out_size, void* d_ws, size_t ws_size,
                              hipStream_t stream) {
  const int B = 4, T = 256, U = 64;
  const float* input_values = (const float*)d_in[0];
  const int* labels = (const int*)d_in[1];
  const float* a_lin_w = (const float*)d_in[4];
  const float* a_lin_b = (const float*)d_in[5];
  const float* a_pos = (const float*)d_in[6];
  const float* l_word = (const float*)d_in[7];
  const float* l_pos = (const float*)d_in[8];
  const float* joint_w = (const float*)d_in[9];
  const float* joint_b = (const float*)d_in[10];
  const float* out_w = (const float*)d_in[11];
  const float* out_b = (const float*)d_in[12];

  const float* a_qkv_w = (const float*)d_in[13];
  const float* a_qkv_b = (const float*)d_in[14];
  const float* a_out_w = (const float*)d_in[15];
  const float* a_out_b = (const float*)d_in[16];
  const float* a_ff1_w = (const float*)d_in[17];
  const float* a_ff1_b = (const float*)d_in[18];
  const float* a_ff2_w = (const float*)d_in[19];
  const float* a_ff2_b = (const float*)d_in[20];
  const float* a_ln1_s = (const float*)d_in[21];
  const float* a_ln1_b = (const float*)d_in[22];
  const float* a_ln2_s = (const float*)d_in[23];
  const float* a_ln2_b = (const float*)d_in[24];
  const float* l_qkv_w = (const float*)d_in[25];
  const float* l_qkv_b = (const float*)d_in[26];
  const float* l_out_w = (const float*)d_in[27];
  const float* l_out_b = (const float*)d_in[28];
  const float* l_ff1_w = (const float*)d_in[29];
  const float* l_ff1_b = (const float*)d_in[30];
  const float* l_ff2_w = (const float*)d_in[31];
  const float* l_ff2_b = (const float*)d_in[32];
  const float* l_ln1_s = (const float*)d_in[33];
  const float* l_ln1_b = (const float*)d_in[34];
  const float* l_ln2_s = (const float*)d_in[35];
  const float* l_ln2_b = (const float*)d_in[36];

  // workspace (floats): x_all 1280x512, qkv 1280x1536, ctx 1280x512,
  // tmp 1280x512, ff1 1280x2048; ha/hl/Wb (bf16) alias qkv after encoders.
  float* ws = (float*)d_ws;
  float* x_all = ws;                       // 655360
  float* qkv   = x_all + 655360;           // 1966080
  float* ctx   = qkv + 1966080;            // 655360
  float* tmp   = ctx + 655360;             // 655360
  float* ff1   = tmp + 655360;             // 2621440
  unsigned short* ha_bf = (unsigned short*)qkv;              // 1048576 f-equiv
  unsigned short* hl_bf = (unsigned short*)(qkv + 1048576);  // 262144 f-equiv
  unsigned short* Wb    = (unsigned short*)(qkv + 1310720);  // 1048576 f-equiv

  // ---- embeddings ----
  embed_audio_kernel<<<B * T, 256, 0, stream>>>(input_values, a_lin_w, a_lin_b,
                                                a_pos, x_all, T);
  embed_label_kernel<<<B * U, 256, 0, stream>>>(labels, l_word, l_pos,
                                                x_all + 1024 * HD, U);

  // ---- merged encoder layers ----
  for (int l = 0; l < 12; l++) {
    bool both = (l < 4);
    int M = both ? 1280 : 1024;
    int gy = M / 64;
    const float* qw1 = both ? l_qkv_w + (size_t)l * 1536 * HD : a_qkv_w;
    const float* qb1 = both ? l_qkv_b + (size_t)l * 1536 : a_qkv_b;
    const float* ow1 = both ? l_out_w + (size_t)l * HD * HD : a_out_w;
    const float* ob1 = both ? l_out_b + (size_t)l * HD : a_out_b;
    const float* f1w1 = both ? l_ff1_w + (size_t)l * FF * HD : a_ff1_w;
    const float* f1b1 = both ? l_ff1_b + (size_t)l * FF : a_ff1_b;
    const float* f2w1 = both ? l_ff2_w + (size_t)l * HD * FF : a_ff2_w;
    const float* f2b1 = both ? l_ff2_b + (size_t)l * HD : a_ff2_b;
    const float* n1s1 = both ? l_ln1_s + (size_t)l * HD : a_ln1_s;
    const float* n1b1 = both ? l_ln1_b + (size_t)l * HD : a_ln1_b;
    const float* n2s1 = both ? l_ln2_s + (size_t)l * HD : a_ln2_s;
    const float* n2b1 = both ? l_ln2_b + (size_t)l * HD : a_ln2_b;

    gemm64_kernel<0, 0><<<dim3(1536 / 64, gy), 256, 0, stream>>>(
        x_all, HD, a_qkv_w + (size_t)l * 1536 * HD, qw1, HD,
        a_qkv_b + (size_t)l * 1536, qb1, qkv, 1536, 1536, HD, 1024);
    attn_kernel<<<dim3(both ? 320 : 256, 8, B), 256, 0, stream>>>(qkv, ctx);
    gemm64_kernel<0, 0><<<dim3(HD / 64, gy), 256, 0, stream>>>(
        ctx, HD, a_out_w + (size_t)l * HD * HD, ow1, HD,
        a_out_b + (size_t)l * HD, ob1, tmp, HD, HD, HD, 1024);
    add_ln_kernel<<<M, 256, 0, stream>>>(x_all, tmp,
        a_ln1_s + (size_t)l * HD, a_ln1_b + (size_t)l * HD, n1s1, n1b1);
    gemm64_kernel<1, 0><<<dim3(FF / 64, gy), 256, 0, stream>>>(
        x_all, HD, a_ff1_w + (size_t)l * FF * HD, f1w1, HD,
        a_ff1_b + (size_t)l * FF, f1b1, ff1, FF, FF, HD, 1024);
    gemm64_kernel<0, 0><<<dim3(HD / 64, gy), 256, 0, stream>>>(
        ff1, FF, a_ff2_w + (size_t)l * HD * FF, f2w1, FF,
        a_ff2_b + (size_t)l * HD, f2b1, tmp, HD, HD, FF, 1024);
    add_ln_kernel<<<M, 256, 0, stream>>>(x_all, tmp,
        a_ln2_s + (size_t)l * HD, a_ln2_b + (size_t)l * HD, n2s1, n2b1);
  }

  // ---- Wb conversion ----
  cvt_bf16_kernel<<<(VOUT * KJOINT) / 1024, 256, 0, stream>>>(out_w, Wb);

  // ---- joint projections -> bf16 ----
  gemm64_kernel<0, 1><<<dim3(KJOINT / 64, 1024 / 64), 256, 0, stream>>>(
      x_all, HD, joint_w, joint_w, 1024, nullptr, nullptr,
      ha_bf, KJOINT, KJOINT, HD, 1 << 30);
  gemm64_kernel<0, 1><<<dim3(KJOINT / 64, 256 / 64), 256, 0, stream>>>(
      x_all + 1024 * HD, HD, joint_w + HD, joint_w + HD, 1024, joint_b, joint_b,
      hl_bf, KJOINT, KJOINT, HD, 1 << 30);

  // ---- fused joint + log_softmax ----
  joint_fused_kernel<<<B * T, 512, 0, stream>>>(
      ha_bf, hl_bf, Wb, out_b, (float*)d_out);
}